// Round 10
// baseline (267.449 us; speedup 1.0000x reference)
//
#include <hip/hip_runtime.h>
#include <math.h>

#define B_ 4
#define S_ 2048
#define E_ 512
#define H_ 8
#define MLP_ 2048

typedef unsigned short u16;
typedef __attribute__((ext_vector_type(8))) short bf16x8;
typedef __attribute__((ext_vector_type(4))) float f32x4;

#define MFMA(a, b, c) __builtin_amdgcn_mfma_f32_16x16x32_bf16(a, b, c, 0, 0, 0)

__device__ __forceinline__ u16 f2bf(float f) {
  unsigned u = __builtin_bit_cast(unsigned, f);
  unsigned r = (u + 0x7FFFu + ((u >> 16) & 1u)) >> 16;
  return (u16)r;
}
__device__ __forceinline__ void gload_lds16(const void* g, void* l) {
  __builtin_amdgcn_global_load_lds(
      (const __attribute__((address_space(1))) unsigned int*)g,
      (__attribute__((address_space(3))) unsigned int*)l, 16, 0, 0);
}

// ---------------- all weights f32 -> bf16 in one launch ----------------
__global__ void cvt4_k(const float* __restrict__ s0, u16* __restrict__ d0,
                       const float* __restrict__ s1, u16* __restrict__ d1,
                       const float* __restrict__ s2, u16* __restrict__ d2,
                       const float* __restrict__ s3, u16* __restrict__ d3) {
  int bid = blockIdx.x;
  const float* s; u16* d; int i;
  if (bid < 768)       { s = s0; d = d0; i = bid * 256 + threadIdx.x; }
  else if (bid < 1024) { s = s1; d = d1; i = (bid - 768) * 256 + threadIdx.x; }
  else if (bid < 2048) { s = s2; d = d2; i = (bid - 1024) * 256 + threadIdx.x; }
  else                 { s = s3; d = d3; i = (bid - 2048) * 256 + threadIdx.x; }
  float4 v = reinterpret_cast<const float4*>(s)[i];
  union { u16 u[4]; uint2 q; } p;
  p.u[0] = f2bf(v.x); p.u[1] = f2bf(v.y); p.u[2] = f2bf(v.z); p.u[3] = f2bf(v.w);
  reinterpret_cast<uint2*>(d)[i] = p.q;
}

// ---------------- LayerNorm (rows of 512) -> bf16 ----------------
__global__ __launch_bounds__(256) void ln_k(const float* __restrict__ x, const float* __restrict__ g,
                                            const float* __restrict__ bta, u16* __restrict__ out) {
  int row = blockIdx.x * 4 + (threadIdx.x >> 6);
  int l = threadIdx.x & 63;
  const float4* xr = reinterpret_cast<const float4*>(x + (size_t)row * 512);
  float4 a = xr[l], c = xr[l + 64];
  float s = a.x + a.y + a.z + a.w + c.x + c.y + c.z + c.w;
  float q = a.x*a.x + a.y*a.y + a.z*a.z + a.w*a.w + c.x*c.x + c.y*c.y + c.z*c.z + c.w*c.w;
  #pragma unroll
  for (int off = 32; off >= 1; off >>= 1) { s += __shfl_xor(s, off); q += __shfl_xor(q, off); }
  float mu = s * (1.0f / 512.0f);
  float var = q * (1.0f / 512.0f) - mu * mu;
  float rs = rsqrtf(var + 1e-5f);
  const float4* gv = reinterpret_cast<const float4*>(g);
  const float4* bv = reinterpret_cast<const float4*>(bta);
  #pragma unroll
  for (int half = 0; half < 2; ++half) {
    int idx = l + half * 64;
    float4 gg = gv[idx], bb = bv[idx];
    float4 vv = (half == 0) ? a : c;
    union { u16 u[4]; uint2 q2; } p;
    p.u[0] = f2bf((vv.x - mu) * rs * gg.x + bb.x);
    p.u[1] = f2bf((vv.y - mu) * rs * gg.y + bb.y);
    p.u[2] = f2bf((vv.z - mu) * rs * gg.z + bb.z);
    p.u[3] = f2bf((vv.w - mu) * rs * gg.w + bb.w);
    *reinterpret_cast<uint2*>(out + (size_t)row * 512 + idx * 4) = p.q2;
  }
}

// ---------------- GEMM (BK=64, swizzled LDS): C = A * W^T + bias ----------------
// EPI 0: -> bf16   EPI 1: + resid(f32) -> f32   EPI 2: gelu -> bf16
// EPI 3: QKV: Q*0.125 -> qkv; K -> qkv; V -> vT[b][h][d][k]
template <int EPI>
__global__ __launch_bounds__(256) void gemm_nt(const u16* __restrict__ A, const u16* __restrict__ Bw,
                                               const float* __restrict__ bias,
                                               const float* __restrict__ resid,
                                               void* __restrict__ Cout, u16* __restrict__ vTout,
                                               int M, int N, int K) {
  __shared__ u16 lA[128 * 64];
  __shared__ u16 lB[128 * 64];
  int t = threadIdx.x, w = t >> 6, l = t & 63;
  int m0 = blockIdx.y * 128, n0 = blockIdx.x * 128;
  int wr = w >> 1, wc = w & 1;
  int rl = l & 15, hi = l >> 4;
  f32x4 zero = {0.f, 0.f, 0.f, 0.f};
  f32x4 acc[4][4];
  #pragma unroll
  for (int mi = 0; mi < 4; ++mi)
    #pragma unroll
    for (int ni = 0; ni < 4; ++ni) acc[mi][ni] = zero;

  for (int k0 = 0; k0 < K; k0 += 64) {
    #pragma unroll
    for (int it = 0; it < 4; ++it) {
      int cid = it * 256 + t;
      int row = cid >> 3, g = cid & 7;
      int gs = (g ^ (row & 7)) * 8;
      gload_lds16(A + (size_t)(m0 + row) * K + k0 + gs, lA + (size_t)cid * 8);
      gload_lds16(Bw + (size_t)(n0 + row) * K + k0 + gs, lB + (size_t)cid * 8);
    }
    __syncthreads();
    #pragma unroll
    for (int kk = 0; kk < 2; ++kk) {
      bf16x8 af[4], bfr[4];
      #pragma unroll
      for (int mi = 0; mi < 4; ++mi) {
        int row = wr * 64 + mi * 16 + rl;
        af[mi] = *reinterpret_cast<const bf16x8*>(&lA[row * 64 + (((kk * 4 + hi) ^ (row & 7)) * 8)]);
      }
      #pragma unroll
      for (int ni = 0; ni < 4; ++ni) {
        int row = wc * 64 + ni * 16 + rl;
        bfr[ni] = *reinterpret_cast<const bf16x8*>(&lB[row * 64 + (((kk * 4 + hi) ^ (row & 7)) * 8)]);
      }
      #pragma unroll
      for (int mi = 0; mi < 4; ++mi)
        #pragma unroll
        for (int ni = 0; ni < 4; ++ni) acc[mi][ni] = MFMA(af[mi], bfr[ni], acc[mi][ni]);
    }
    __syncthreads();
  }
  int rg = hi * 4;
  #pragma unroll
  for (int mi = 0; mi < 4; ++mi) {
    #pragma unroll
    for (int ni = 0; ni < 4; ++ni) {
      int gn = n0 + wc * 64 + ni * 16 + rl;
      float bvv = bias[gn];
      #pragma unroll
      for (int r = 0; r < 4; ++r) {
        int gm = m0 + wr * 64 + mi * 16 + rg + r;
        size_t off = (size_t)gm * N + gn;
        float v = acc[mi][ni][r] + bvv;
        if (EPI == 0) {
          ((u16*)Cout)[off] = f2bf(v);
        } else if (EPI == 1) {
          ((float*)Cout)[off] = v + resid[off];
        } else if (EPI == 2) {
          float gl = 0.5f * v * (1.0f + erff(v * 0.70710678118654752f));
          ((u16*)Cout)[off] = f2bf(gl);
        } else {
          int key = gm & 2047, bb = gm >> 11;
          if (gn < 512) {
            ((u16*)Cout)[off] = f2bf(v * 0.125f);
          } else if (gn < 1024) {
            ((u16*)Cout)[off] = f2bf(v);
          } else {
            int d = gn - 1024;             // h*64 + dim
            vTout[((size_t)(bb * 8 + (d >> 6)) * 64 + (d & 63)) * 2048 + key] = f2bf(v);
          }
        }
      }
    }
  }
}

// ---------------- Split-K flash ctx: partial (unnormalized) acc + partial rowsum ----------------
// blockIdx.x = qblk*2 + ks; keys [ks*1024, ks*1024+1024). 1024 blocks -> 3 blocks/CU (LDS).
__global__ __launch_bounds__(256) void attn_fctx3_k(const u16* __restrict__ qkv,
                                                    const u16* __restrict__ vT,
                                                    float* __restrict__ pacc,
                                                    float* __restrict__ plsum) {
  __shared__ u16 kbuf[2][64 * 64];
  __shared__ u16 vbuf[2][64 * 64];
  __shared__ u16 pl[4][32][72];
  int t = threadIdx.x, w = t >> 6, l = t & 63;
  int h = blockIdx.y, b = blockIdx.z;
  int qblk = blockIdx.x >> 1, ks = blockIdx.x & 1;
  int qt = qblk * 128 + w * 32;
  int kbase = ks * 1024;
  int rl = l & 15, hi = l >> 4;
  f32x4 zero = {0.f, 0.f, 0.f, 0.f};
  bf16x8 qf_[2][2];
  #pragma unroll
  for (int qf = 0; qf < 2; ++qf)
    #pragma unroll
    for (int hf = 0; hf < 2; ++hf)
      qf_[qf][hf] = *reinterpret_cast<const bf16x8*>(
          qkv + (size_t)(b * S_ + qt + qf * 16 + rl) * 1536 + h * 64 + hf * 32 + hi * 8);
  f32x4 acc[2][4];
  float lsp[2][4];
  #pragma unroll
  for (int qf = 0; qf < 2; ++qf) {
    #pragma unroll
    for (int dc = 0; dc < 4; ++dc) acc[qf][dc] = zero;
    #pragma unroll
    for (int r = 0; r < 4; ++r) lsp[qf][r] = 0.f;
  }
  // stage tile 0
  #pragma unroll
  for (int it = 0; it < 2; ++it) {
    int c = it * 256 + t;
    int r = c >> 3, gp = c & 7, gl = gp ^ (r & 7);
    gload_lds16(qkv + (size_t)(b * S_ + kbase + r) * 1536 + 512 + h * 64 + gl * 8, &kbuf[0][c * 8]);
    gload_lds16(vT + ((size_t)(b * H_ + h) * 64 + r) * 2048 + kbase + gl * 8, &vbuf[0][c * 8]);
  }
  __syncthreads();
  for (int kt = 0; kt < 16; ++kt) {
    int cur = kt & 1;
    const u16* kb = kbuf[cur];
    const u16* vb = vbuf[cur];
    f32x4 s[2][4];
    __builtin_amdgcn_s_setprio(1);
    #pragma unroll
    for (int j = 0; j < 4; ++j) {
      int row = j * 16 + rl;
      bf16x8 k0 = *reinterpret_cast<const bf16x8*>(kb + row * 64 + ((hi ^ (row & 7)) * 8));
      bf16x8 k1 = *reinterpret_cast<const bf16x8*>(kb + row * 64 + (((hi + 4) ^ (row & 7)) * 8));
      s[0][j] = MFMA(qf_[0][0], k0, zero);
      s[0][j] = MFMA(qf_[0][1], k1, s[0][j]);
      s[1][j] = MFMA(qf_[1][0], k0, zero);
      s[1][j] = MFMA(qf_[1][1], k1, s[1][j]);
    }
    __builtin_amdgcn_s_setprio(0);
    // p = exp(s) (scale pre-folded into Q); per-lane partial row sums
    #pragma unroll
    for (int qf = 0; qf < 2; ++qf)
      #pragma unroll
      for (int j = 0; j < 4; ++j)
        #pragma unroll
        for (int r = 0; r < 4; ++r) {
          float p = __expf(s[qf][j][r]);
          pl[w][qf * 16 + hi * 4 + r][j * 16 + rl] = f2bf(p);
          lsp[qf][r] += p;
        }
    // prefetch next tile into the other buffer (async; drained at barrier)
    if (kt + 1 < 16) {
      #pragma unroll
      for (int it = 0; it < 2; ++it) {
        int c = it * 256 + t;
        int r = c >> 3, gp = c & 7, gl = gp ^ (r & 7);
        gload_lds16(qkv + (size_t)(b * S_ + kbase + (kt + 1) * 64 + r) * 1536 + 512 + h * 64 + gl * 8,
                    &kbuf[cur ^ 1][c * 8]);
        gload_lds16(vT + ((size_t)(b * H_ + h) * 64 + r) * 2048 + kbase + (kt + 1) * 64 + gl * 8,
                    &vbuf[cur ^ 1][c * 8]);
      }
    }
    // PV (pl is per-wave: same-wave DS write->read needs no barrier)
    bf16x8 pf[2][2];
    #pragma unroll
    for (int qf = 0; qf < 2; ++qf) {
      pf[qf][0] = *reinterpret_cast<const bf16x8*>(&pl[w][qf * 16 + rl][hi * 8]);
      pf[qf][1] = *reinterpret_cast<const bf16x8*>(&pl[w][qf * 16 + rl][32 + hi * 8]);
    }
    __builtin_amdgcn_s_setprio(1);
    #pragma unroll
    for (int dc = 0; dc < 4; ++dc) {
      int row = dc * 16 + rl;
      bf16x8 v0 = *reinterpret_cast<const bf16x8*>(vb + row * 64 + ((hi ^ (row & 7)) * 8));
      bf16x8 v1 = *reinterpret_cast<const bf16x8*>(vb + row * 64 + (((hi + 4) ^ (row & 7)) * 8));
      acc[0][dc] = MFMA(pf[0][0], v0, acc[0][dc]);
      acc[0][dc] = MFMA(pf[0][1], v1, acc[0][dc]);
      acc[1][dc] = MFMA(pf[1][0], v0, acc[1][dc]);
      acc[1][dc] = MFMA(pf[1][1], v1, acc[1][dc]);
    }
    __builtin_amdgcn_s_setprio(0);
    __syncthreads();
  }
  // finish partial row sums (reduce over the 16 rl lanes)
  #pragma unroll
  for (int qf = 0; qf < 2; ++qf)
    #pragma unroll
    for (int r = 0; r < 4; ++r) {
      float v = lsp[qf][r];
      #pragma unroll
      for (int off = 8; off >= 1; off >>= 1) v += __shfl_xor(v, off, 16);
      lsp[qf][r] = v;
    }
  size_t sbase = ((size_t)(ks * 4 + b) * 8 + h) * 2048;
  #pragma unroll
  for (int qf = 0; qf < 2; ++qf)
    #pragma unroll
    for (int dc = 0; dc < 4; ++dc)
      #pragma unroll
      for (int r = 0; r < 4; ++r)
        pacc[(sbase + qt + qf * 16 + hi * 4 + r) * 64 + dc * 16 + rl] = acc[qf][dc][r];
  if (rl == 0) {
    #pragma unroll
    for (int qf = 0; qf < 2; ++qf)
      #pragma unroll
      for (int r = 0; r < 4; ++r)
        plsum[sbase + qt + qf * 16 + hi * 4 + r] = lsp[qf][r];
  }
}

// ---------------- combine split-K partials: ctx (bf16) + rinv ----------------
__global__ __launch_bounds__(256) void fcomb_k(const float* __restrict__ pacc,
                                               const float* __restrict__ plsum,
                                               u16* __restrict__ ctx,
                                               float* __restrict__ rinv) {
  int t = threadIdx.x;
  int qc = blockIdx.x, h = blockIdx.y, b = blockIdx.z;
  int q = qc * 32 + (t >> 3), d0 = (t & 7) * 8;
  size_t i0 = ((size_t)(b) * 8 + h) * 2048 + q;
  size_t i1 = ((size_t)(4 + b) * 8 + h) * 2048 + q;
  float4 a0 = *reinterpret_cast<const float4*>(pacc + i0 * 64 + d0);
  float4 a1 = *reinterpret_cast<const float4*>(pacc + i0 * 64 + d0 + 4);
  float4 c0 = *reinterpret_cast<const float4*>(pacc + i1 * 64 + d0);
  float4 c1 = *reinterpret_cast<const float4*>(pacc + i1 * 64 + d0 + 4);
  float lv = plsum[i0] + plsum[i1];
  float inv = 1.0f / lv;
  union { u16 u[8]; uint4 v; } o;
  o.u[0] = f2bf((a0.x + c0.x) * inv); o.u[1] = f2bf((a0.y + c0.y) * inv);
  o.u[2] = f2bf((a0.z + c0.z) * inv); o.u[3] = f2bf((a0.w + c0.w) * inv);
  o.u[4] = f2bf((a1.x + c1.x) * inv); o.u[5] = f2bf((a1.y + c1.y) * inv);
  o.u[6] = f2bf((a1.z + c1.z) * inv); o.u[7] = f2bf((a1.w + c1.w) * inv);
  *reinterpret_cast<uint4*>(ctx + ((size_t)(b * S_ + q) * 512 + h * 64 + d0)) = o.v;
  if ((t & 7) == 0) rinv[((size_t)b * 8 + h) * 2048 + q] = 0.125f * inv;
}

// ---------------- head-mean probs v8: 128x128 GEMM-shaped, head-looped epilogue ----------------
__global__ __launch_bounds__(256) void attn_mean8_k(const u16* __restrict__ qkv,
                                                    const float* __restrict__ rinv,
                                                    float* __restrict__ attn) {
  __shared__ u16 lQ[128 * 64];
  __shared__ u16 lK[128 * 64];
  int t = threadIdx.x, w = t >> 6, l = t & 63;
  int kt = blockIdx.x, qt = blockIdx.y, b = blockIdx.z;
  int wr = w >> 1, wc = w & 1;
  int rl = l & 15, hi = l >> 4;
  f32x4 zero = {0.f, 0.f, 0.f, 0.f};
  f32x4 acc[4][4];
  #pragma unroll
  for (int mi = 0; mi < 4; ++mi)
    #pragma unroll
    for (int ni = 0; ni < 4; ++ni) acc[mi][ni] = zero;

  const u16* qbase = qkv + (size_t)(b * S_ + qt * 128) * 1536;
  const u16* kbase = qkv + (size_t)(b * S_ + kt * 128) * 1536 + 512;
  for (int h = 0; h < 8; ++h) {
    #pragma unroll
    for (int it = 0; it < 4; ++it) {
      int cid = it * 256 + t;
      int row = cid >> 3, g = cid & 7;
      int gs = (g ^ (row & 7)) * 8;
      gload_lds16(qbase + (size_t)row * 1536 + h * 64 + gs, lQ + (size_t)cid * 8);
      gload_lds16(kbase + (size_t)row * 1536 + h * 64 + gs, lK + (size_t)cid * 8);
    }
    __syncthreads();
    float4 rv[4];
    #pragma unroll
    for (int mi = 0; mi < 4; ++mi)
      rv[mi] = *reinterpret_cast<const float4*>(
          rinv + (size_t)(b * H_ + h) * S_ + qt * 128 + wr * 64 + mi * 16 + hi * 4);
    f32x4 s[4][4];
    #pragma unroll
    for (int kk = 0; kk < 2; ++kk) {
      bf16x8 af[4], bfr[4];
      #pragma unroll
      for (int mi = 0; mi < 4; ++mi) {
        int row = wr * 64 + mi * 16 + rl;
        af[mi] = *reinterpret_cast<const bf16x8*>(&lQ[row * 64 + (((kk * 4 + hi) ^ (row & 7)) * 8)]);
      }
      #pragma unroll
      for (int ni = 0; ni < 4; ++ni) {
        int row = wc * 64 + ni * 16 + rl;
        bfr[ni] = *reinterpret_cast<const bf16x8*>(&lK[row * 64 + (((kk * 4 + hi) ^ (row & 7)) * 8)]);
      }
      #pragma unroll
      for (int mi = 0; mi < 4; ++mi)
        #pragma unroll
        for (int ni = 0; ni < 4; ++ni)
          s[mi][ni] = (kk == 0) ? MFMA(af[mi], bfr[ni], zero) : MFMA(af[mi], bfr[ni], s[mi][ni]);
    }
    #pragma unroll
    for (int mi = 0; mi < 4; ++mi) {
      float rva[4] = {rv[mi].x, rv[mi].y, rv[mi].z, rv[mi].w};
      #pragma unroll
      for (int ni = 0; ni < 4; ++ni)
        #pragma unroll
        for (int r = 0; r < 4; ++r)
          acc[mi][ni][r] += __expf(s[mi][ni][r]) * rva[r];
    }
    __syncthreads();
  }
  #pragma unroll
  for (int mi = 0; mi < 4; ++mi)
    #pragma unroll
    for (int r = 0; r < 4; ++r) {
      size_t rowoff = (size_t)(b * S_ + qt * 128 + wr * 64 + mi * 16 + hi * 4 + r) * 2048 +
                      kt * 128 + wc * 64 + rl;
      #pragma unroll
      for (int ni = 0; ni < 4; ++ni)
        attn[rowoff + ni * 16] = acc[mi][ni][r];
    }
}

// ---------------- launcher ----------------
extern "C" void kernel_launch(void* const* d_in, const int* in_sizes, int n_in,
                              void* d_out, int out_size, void* d_ws, size_t ws_size,
                              hipStream_t stream) {
  const float* query     = (const float*)d_in[0];
  const float* ln1_g     = (const float*)d_in[1];
  const float* ln1_b     = (const float*)d_in[2];
  const float* in_proj_w = (const float*)d_in[3];
  const float* in_proj_b = (const float*)d_in[4];
  const float* out_w     = (const float*)d_in[5];
  const float* out_b     = (const float*)d_in[6];
  const float* ln2_g     = (const float*)d_in[7];
  const float* ln2_b     = (const float*)d_in[8];
  const float* w1        = (const float*)d_in[9];
  const float* b1        = (const float*)d_in[10];
  const float* w2        = (const float*)d_in[11];
  const float* b2        = (const float*)d_in[12];

  u16* ws = (u16*)d_ws;
  u16* wq_bf = ws;                       // [1536,512]
  u16* wo_bf = wq_bf + 1536 * 512;       // [512,512]
  u16* w1_bf = wo_bf + 512 * 512;        // [2048,512]
  u16* w2_bf = w1_bf + 2048 * 512;       // [512,2048]
  u16* xq_bf = w2_bf + 512 * 2048;       // [8192,512]
  u16* qkv_bf = xq_bf + 8192 * 512;      // [8192,1536] (V section unused)
  u16* ctx_bf = qkv_bf + 8192 * 1536;    // [8192,512]
  u16* h_bf   = ctx_bf + 8192 * 512;     // [8192,512]
  u16* mh_bf  = h_bf + 8192 * 512;       // [8192,2048]
  float* rinv = (float*)(mh_bf + 8192 * 2048);  // [B*H*S]
  float* plsum = rinv + 65536;                  // [2*B*H*S] split-K partial sums
  u16* vT = mh_bf;                       // [4,8,64,2048] alias (mh dead until MLP1)

  float* xout = (float*)d_out;                    // [8192,512]
  float* attn = xout + (size_t)8192 * 512;        // [4,2048,2048]
  float* pacc = attn;                    // split-K partial ctx (33.5MB) aliased onto attn;
                                         // mean8 later overwrites every attn element.

  // 1. weights -> bf16 (single fused launch)
  cvt4_k<<<3072, 256, 0, stream>>>(in_proj_w, wq_bf, out_w, wo_bf, w1, w1_bf, w2, w2_bf);

  // 2. LN1
  ln_k<<<2048, 256, 0, stream>>>(query, ln1_g, ln1_b, xq_bf);

  // 3. QKV projection (Q pre-scaled 0.125; V transposed to vT)
  gemm_nt<3><<<dim3(12, 64), 256, 0, stream>>>(xq_bf, wq_bf, in_proj_b, nullptr, qkv_bf, vT, 8192, 1536, 512);

  // 4. split-K flash ctx partials
  attn_fctx3_k<<<dim3(32, 8, 4), 256, 0, stream>>>(qkv_bf, vT, pacc, plsum);

  // 5. combine partials -> ctx (bf16) + rinv
  fcomb_k<<<dim3(64, 8, 4), 256, 0, stream>>>(pacc, plsum, ctx_bf, rinv);

  // 6. head-mean probs -> attn_weight output (GEMM-shaped; overwrites pacc region)
  attn_mean8_k<<<dim3(16, 16, 4), 256, 0, stream>>>(qkv_bf, rinv, attn);

  // 7. out-proj + residual(query) -> x (f32, d_out)
  gemm_nt<1><<<dim3(4, 64), 256, 0, stream>>>(ctx_bf, wo_bf, out_b, query, xout, nullptr, 8192, 512, 512);

  // 8. LN2 on x
  ln_k<<<2048, 256, 0, stream>>>(xout, ln2_g, ln2_b, h_bf);

  // 9. MLP up + GELU
  gemm_nt<2><<<dim3(16, 64), 256, 0, stream>>>(h_bf, w1_bf, b1, nullptr, mh_bf, nullptr, 8192, 2048, 512);

  // 10. MLP down + residual(x) -> final x (in-place on d_out x region)
  gemm_nt<1><<<dim3(4, 64), 256, 0, stream>>>(mh_bf, w2_bf, b2, xout, xout, nullptr, 8192, 512, 2048);
}

// Round 11
// 258.879 us; speedup vs baseline: 1.0331x; 1.0331x over previous
//
#include <hip/hip_runtime.h>
#include <math.h>

#define B_ 4
#define S_ 2048
#define E_ 512
#define H_ 8
#define MLP_ 2048

typedef unsigned short u16;
typedef __attribute__((ext_vector_type(8))) short bf16x8;
typedef __attribute__((ext_vector_type(4))) float f32x4;

#define MFMA(a, b, c) __builtin_amdgcn_mfma_f32_16x16x32_bf16(a, b, c, 0, 0, 0)
// Q pre-scale: (1/8) * log2(e)  -> scores land in log2 domain; exp2f = bare v_exp_f32
#define QSCALE 0.18033688011112042f

__device__ __forceinline__ u16 f2bf(float f) {
  unsigned u = __builtin_bit_cast(unsigned, f);
  unsigned r = (u + 0x7FFFu + ((u >> 16) & 1u)) >> 16;
  return (u16)r;
}
// cheap round-half-up for positive P values feeding bf16 MFMA
__device__ __forceinline__ u16 f2bfp(float f) {
  return (u16)((__builtin_bit_cast(unsigned, f) + 0x8000u) >> 16);
}
__device__ __forceinline__ void gload_lds16(const void* g, void* l) {
  __builtin_amdgcn_global_load_lds(
      (const __attribute__((address_space(1))) unsigned int*)g,
      (__attribute__((address_space(3))) unsigned int*)l, 16, 0, 0);
}

// ---------------- all weights f32 -> bf16 in one launch ----------------
__global__ void cvt4_k(const float* __restrict__ s0, u16* __restrict__ d0,
                       const float* __restrict__ s1, u16* __restrict__ d1,
                       const float* __restrict__ s2, u16* __restrict__ d2,
                       const float* __restrict__ s3, u16* __restrict__ d3) {
  int bid = blockIdx.x;
  const float* s; u16* d; int i;
  if (bid < 768)       { s = s0; d = d0; i = bid * 256 + threadIdx.x; }
  else if (bid < 1024) { s = s1; d = d1; i = (bid - 768) * 256 + threadIdx.x; }
  else if (bid < 2048) { s = s2; d = d2; i = (bid - 1024) * 256 + threadIdx.x; }
  else                 { s = s3; d = d3; i = (bid - 2048) * 256 + threadIdx.x; }
  float4 v = reinterpret_cast<const float4*>(s)[i];
  union { u16 u[4]; uint2 q; } p;
  p.u[0] = f2bf(v.x); p.u[1] = f2bf(v.y); p.u[2] = f2bf(v.z); p.u[3] = f2bf(v.w);
  reinterpret_cast<uint2*>(d)[i] = p.q;
}

// ---------------- LayerNorm (rows of 512) -> bf16 ----------------
__global__ __launch_bounds__(256) void ln_k(const float* __restrict__ x, const float* __restrict__ g,
                                            const float* __restrict__ bta, u16* __restrict__ out) {
  int row = blockIdx.x * 4 + (threadIdx.x >> 6);
  int l = threadIdx.x & 63;
  const float4* xr = reinterpret_cast<const float4*>(x + (size_t)row * 512);
  float4 a = xr[l], c = xr[l + 64];
  float s = a.x + a.y + a.z + a.w + c.x + c.y + c.z + c.w;
  float q = a.x*a.x + a.y*a.y + a.z*a.z + a.w*a.w + c.x*c.x + c.y*c.y + c.z*c.z + c.w*c.w;
  #pragma unroll
  for (int off = 32; off >= 1; off >>= 1) { s += __shfl_xor(s, off); q += __shfl_xor(q, off); }
  float mu = s * (1.0f / 512.0f);
  float var = q * (1.0f / 512.0f) - mu * mu;
  float rs = rsqrtf(var + 1e-5f);
  const float4* gv = reinterpret_cast<const float4*>(g);
  const float4* bv = reinterpret_cast<const float4*>(bta);
  #pragma unroll
  for (int half = 0; half < 2; ++half) {
    int idx = l + half * 64;
    float4 gg = gv[idx], bb = bv[idx];
    float4 vv = (half == 0) ? a : c;
    union { u16 u[4]; uint2 q2; } p;
    p.u[0] = f2bf((vv.x - mu) * rs * gg.x + bb.x);
    p.u[1] = f2bf((vv.y - mu) * rs * gg.y + bb.y);
    p.u[2] = f2bf((vv.z - mu) * rs * gg.z + bb.z);
    p.u[3] = f2bf((vv.w - mu) * rs * gg.w + bb.w);
    *reinterpret_cast<uint2*>(out + (size_t)row * 512 + idx * 4) = p.q2;
  }
}

// ---------------- GEMM (BK=64, swizzled LDS): C = A * W^T + bias ----------------
// EPI 0: -> bf16   EPI 1: + resid(f32) -> f32   EPI 2: gelu -> bf16
// EPI 3: QKV: Q*QSCALE -> qkv; K -> qkv; V -> vT[b][h][d][k]
template <int EPI>
__global__ __launch_bounds__(256) void gemm_nt(const u16* __restrict__ A, const u16* __restrict__ Bw,
                                               const float* __restrict__ bias,
                                               const float* __restrict__ resid,
                                               void* __restrict__ Cout, u16* __restrict__ vTout,
                                               int M, int N, int K) {
  __shared__ u16 lA[128 * 64];
  __shared__ u16 lB[128 * 64];
  int t = threadIdx.x, w = t >> 6, l = t & 63;
  int m0 = blockIdx.y * 128, n0 = blockIdx.x * 128;
  int wr = w >> 1, wc = w & 1;
  int rl = l & 15, hi = l >> 4;
  f32x4 zero = {0.f, 0.f, 0.f, 0.f};
  f32x4 acc[4][4];
  #pragma unroll
  for (int mi = 0; mi < 4; ++mi)
    #pragma unroll
    for (int ni = 0; ni < 4; ++ni) acc[mi][ni] = zero;

  for (int k0 = 0; k0 < K; k0 += 64) {
    #pragma unroll
    for (int it = 0; it < 4; ++it) {
      int cid = it * 256 + t;
      int row = cid >> 3, g = cid & 7;
      int gs = (g ^ (row & 7)) * 8;
      gload_lds16(A + (size_t)(m0 + row) * K + k0 + gs, lA + (size_t)cid * 8);
      gload_lds16(Bw + (size_t)(n0 + row) * K + k0 + gs, lB + (size_t)cid * 8);
    }
    __syncthreads();
    #pragma unroll
    for (int kk = 0; kk < 2; ++kk) {
      bf16x8 af[4], bfr[4];
      #pragma unroll
      for (int mi = 0; mi < 4; ++mi) {
        int row = wr * 64 + mi * 16 + rl;
        af[mi] = *reinterpret_cast<const bf16x8*>(&lA[row * 64 + (((kk * 4 + hi) ^ (row & 7)) * 8)]);
      }
      #pragma unroll
      for (int ni = 0; ni < 4; ++ni) {
        int row = wc * 64 + ni * 16 + rl;
        bfr[ni] = *reinterpret_cast<const bf16x8*>(&lB[row * 64 + (((kk * 4 + hi) ^ (row & 7)) * 8)]);
      }
      #pragma unroll
      for (int mi = 0; mi < 4; ++mi)
        #pragma unroll
        for (int ni = 0; ni < 4; ++ni) acc[mi][ni] = MFMA(af[mi], bfr[ni], acc[mi][ni]);
    }
    __syncthreads();
  }
  int rg = hi * 4;
  #pragma unroll
  for (int mi = 0; mi < 4; ++mi) {
    #pragma unroll
    for (int ni = 0; ni < 4; ++ni) {
      int gn = n0 + wc * 64 + ni * 16 + rl;
      float bvv = bias[gn];
      #pragma unroll
      for (int r = 0; r < 4; ++r) {
        int gm = m0 + wr * 64 + mi * 16 + rg + r;
        size_t off = (size_t)gm * N + gn;
        float v = acc[mi][ni][r] + bvv;
        if (EPI == 0) {
          ((u16*)Cout)[off] = f2bf(v);
        } else if (EPI == 1) {
          ((float*)Cout)[off] = v + resid[off];
        } else if (EPI == 2) {
          float gl = 0.5f * v * (1.0f + erff(v * 0.70710678118654752f));
          ((u16*)Cout)[off] = f2bf(gl);
        } else {
          int key = gm & 2047, bb = gm >> 11;
          if (gn < 512) {
            ((u16*)Cout)[off] = f2bf(v * QSCALE);
          } else if (gn < 1024) {
            ((u16*)Cout)[off] = f2bf(v);
          } else {
            int d = gn - 1024;             // h*64 + dim
            vTout[((size_t)(bb * 8 + (d >> 6)) * 64 + (d & 63)) * 2048 + key] = f2bf(v);
          }
        }
      }
    }
  }
}

// ---------------- Fused flash ctx v4: 8 waves share K/V staging; 16 waves/CU ----------------
// exp2f (Q pre-scaled by log2e/8) -> bare v_exp_f32; P rounding = cheap half-up.
__global__ __launch_bounds__(512) void attn_fctx4_k(const u16* __restrict__ qkv,
                                                    const u16* __restrict__ vT,
                                                    float* __restrict__ rinv,
                                                    u16* __restrict__ ctx) {
  __shared__ u16 kbuf[2][64 * 64];
  __shared__ u16 vbuf[2][64 * 64];
  __shared__ u16 pl[8][32][72];
  int t = threadIdx.x, w = t >> 6, l = t & 63;
  int h = blockIdx.y, b = blockIdx.z;
  int qt = blockIdx.x * 256 + w * 32;
  int rl = l & 15, hi = l >> 4;
  f32x4 zero = {0.f, 0.f, 0.f, 0.f};
  bf16x8 qf_[2][2];
  #pragma unroll
  for (int qf = 0; qf < 2; ++qf)
    #pragma unroll
    for (int hf = 0; hf < 2; ++hf)
      qf_[qf][hf] = *reinterpret_cast<const bf16x8*>(
          qkv + (size_t)(b * S_ + qt + qf * 16 + rl) * 1536 + h * 64 + hf * 32 + hi * 8);
  f32x4 acc[2][4];
  float lsp[2][4];
  #pragma unroll
  for (int qf = 0; qf < 2; ++qf) {
    #pragma unroll
    for (int dc = 0; dc < 4; ++dc) acc[qf][dc] = zero;
    #pragma unroll
    for (int r = 0; r < 4; ++r) lsp[qf][r] = 0.f;
  }
  // stage tile 0: one 16B load per thread per buffer (512 threads cover 64x64)
  {
    int c = t;
    int r = c >> 3, gp = c & 7, gl = gp ^ (r & 7);
    gload_lds16(qkv + (size_t)(b * S_ + r) * 1536 + 512 + h * 64 + gl * 8, &kbuf[0][c * 8]);
    gload_lds16(vT + ((size_t)(b * H_ + h) * 64 + r) * 2048 + gl * 8, &vbuf[0][c * 8]);
  }
  __syncthreads();
  for (int kt = 0; kt < 32; ++kt) {
    int cur = kt & 1;
    const u16* kb = kbuf[cur];
    const u16* vb = vbuf[cur];
    f32x4 s[2][4];
    __builtin_amdgcn_s_setprio(1);
    #pragma unroll
    for (int j = 0; j < 4; ++j) {
      int row = j * 16 + rl;
      bf16x8 k0 = *reinterpret_cast<const bf16x8*>(kb + row * 64 + ((hi ^ (row & 7)) * 8));
      bf16x8 k1 = *reinterpret_cast<const bf16x8*>(kb + row * 64 + (((hi + 4) ^ (row & 7)) * 8));
      s[0][j] = MFMA(qf_[0][0], k0, zero);
      s[0][j] = MFMA(qf_[0][1], k1, s[0][j]);
      s[1][j] = MFMA(qf_[1][0], k0, zero);
      s[1][j] = MFMA(qf_[1][1], k1, s[1][j]);
    }
    __builtin_amdgcn_s_setprio(0);
    // p = exp2(s); per-lane partial row sums
    #pragma unroll
    for (int qf = 0; qf < 2; ++qf)
      #pragma unroll
      for (int j = 0; j < 4; ++j)
        #pragma unroll
        for (int r = 0; r < 4; ++r) {
          float p = exp2f(s[qf][j][r]);
          pl[w][qf * 16 + hi * 4 + r][j * 16 + rl] = f2bfp(p);
          lsp[qf][r] += p;
        }
    // prefetch next tile (async; drained at barrier)
    if (kt + 1 < 32) {
      int c = t;
      int r = c >> 3, gp = c & 7, gl = gp ^ (r & 7);
      gload_lds16(qkv + (size_t)(b * S_ + (kt + 1) * 64 + r) * 1536 + 512 + h * 64 + gl * 8,
                  &kbuf[cur ^ 1][c * 8]);
      gload_lds16(vT + ((size_t)(b * H_ + h) * 64 + r) * 2048 + (kt + 1) * 64 + gl * 8,
                  &vbuf[cur ^ 1][c * 8]);
    }
    // PV (pl is per-wave: same-wave DS write->read needs no barrier)
    bf16x8 pf[2][2];
    #pragma unroll
    for (int qf = 0; qf < 2; ++qf) {
      pf[qf][0] = *reinterpret_cast<const bf16x8*>(&pl[w][qf * 16 + rl][hi * 8]);
      pf[qf][1] = *reinterpret_cast<const bf16x8*>(&pl[w][qf * 16 + rl][32 + hi * 8]);
    }
    __builtin_amdgcn_s_setprio(1);
    #pragma unroll
    for (int dc = 0; dc < 4; ++dc) {
      int row = dc * 16 + rl;
      bf16x8 v0 = *reinterpret_cast<const bf16x8*>(vb + row * 64 + ((hi ^ (row & 7)) * 8));
      bf16x8 v1 = *reinterpret_cast<const bf16x8*>(vb + row * 64 + (((hi + 4) ^ (row & 7)) * 8));
      acc[0][dc] = MFMA(pf[0][0], v0, acc[0][dc]);
      acc[0][dc] = MFMA(pf[0][1], v1, acc[0][dc]);
      acc[1][dc] = MFMA(pf[1][0], v0, acc[1][dc]);
      acc[1][dc] = MFMA(pf[1][1], v1, acc[1][dc]);
    }
    __builtin_amdgcn_s_setprio(0);
    __syncthreads();
  }
  // finish row sums (reduce over the 16 rl lanes)
  #pragma unroll
  for (int qf = 0; qf < 2; ++qf)
    #pragma unroll
    for (int r = 0; r < 4; ++r) {
      float v = lsp[qf][r];
      #pragma unroll
      for (int off = 8; off >= 1; off >>= 1) v += __shfl_xor(v, off, 16);
      lsp[qf][r] = v;
    }
  #pragma unroll
  for (int qf = 0; qf < 2; ++qf)
    #pragma unroll
    for (int dc = 0; dc < 4; ++dc)
      #pragma unroll
      for (int r = 0; r < 4; ++r)
        ctx[(size_t)(b * S_ + qt + qf * 16 + hi * 4 + r) * 512 + h * 64 + dc * 16 + rl] =
            f2bf(acc[qf][dc][r] / lsp[qf][r]);
  if (rl == 0) {
    #pragma unroll
    for (int qf = 0; qf < 2; ++qf)
      #pragma unroll
      for (int r = 0; r < 4; ++r)
        rinv[(size_t)(b * H_ + h) * S_ + qt + qf * 16 + hi * 4 + r] = 0.125f / lsp[qf][r];
  }
}

// ---------------- head-mean probs v8: 128x128 GEMM-shaped, head-looped epilogue ----------------
__global__ __launch_bounds__(256) void attn_mean8_k(const u16* __restrict__ qkv,
                                                    const float* __restrict__ rinv,
                                                    float* __restrict__ attn) {
  __shared__ u16 lQ[128 * 64];
  __shared__ u16 lK[128 * 64];
  int t = threadIdx.x, w = t >> 6, l = t & 63;
  int kt = blockIdx.x, qt = blockIdx.y, b = blockIdx.z;
  int wr = w >> 1, wc = w & 1;
  int rl = l & 15, hi = l >> 4;
  f32x4 zero = {0.f, 0.f, 0.f, 0.f};
  f32x4 acc[4][4];
  #pragma unroll
  for (int mi = 0; mi < 4; ++mi)
    #pragma unroll
    for (int ni = 0; ni < 4; ++ni) acc[mi][ni] = zero;

  const u16* qbase = qkv + (size_t)(b * S_ + qt * 128) * 1536;
  const u16* kbase = qkv + (size_t)(b * S_ + kt * 128) * 1536 + 512;
  for (int h = 0; h < 8; ++h) {
    #pragma unroll
    for (int it = 0; it < 4; ++it) {
      int cid = it * 256 + t;
      int row = cid >> 3, g = cid & 7;
      int gs = (g ^ (row & 7)) * 8;
      gload_lds16(qbase + (size_t)row * 1536 + h * 64 + gs, lQ + (size_t)cid * 8);
      gload_lds16(kbase + (size_t)row * 1536 + h * 64 + gs, lK + (size_t)cid * 8);
    }
    __syncthreads();
    float4 rv[4];
    #pragma unroll
    for (int mi = 0; mi < 4; ++mi)
      rv[mi] = *reinterpret_cast<const float4*>(
          rinv + (size_t)(b * H_ + h) * S_ + qt * 128 + wr * 64 + mi * 16 + hi * 4);
    f32x4 s[4][4];
    #pragma unroll
    for (int kk = 0; kk < 2; ++kk) {
      bf16x8 af[4], bfr[4];
      #pragma unroll
      for (int mi = 0; mi < 4; ++mi) {
        int row = wr * 64 + mi * 16 + rl;
        af[mi] = *reinterpret_cast<const bf16x8*>(&lQ[row * 64 + (((kk * 4 + hi) ^ (row & 7)) * 8)]);
      }
      #pragma unroll
      for (int ni = 0; ni < 4; ++ni) {
        int row = wc * 64 + ni * 16 + rl;
        bfr[ni] = *reinterpret_cast<const bf16x8*>(&lK[row * 64 + (((kk * 4 + hi) ^ (row & 7)) * 8)]);
      }
      #pragma unroll
      for (int mi = 0; mi < 4; ++mi)
        #pragma unroll
        for (int ni = 0; ni < 4; ++ni)
          s[mi][ni] = (kk == 0) ? MFMA(af[mi], bfr[ni], zero) : MFMA(af[mi], bfr[ni], s[mi][ni]);
    }
    #pragma unroll
    for (int mi = 0; mi < 4; ++mi) {
      float rva[4] = {rv[mi].x, rv[mi].y, rv[mi].z, rv[mi].w};
      #pragma unroll
      for (int ni = 0; ni < 4; ++ni)
        #pragma unroll
        for (int r = 0; r < 4; ++r)
          acc[mi][ni][r] += exp2f(s[mi][ni][r]) * rva[r];
    }
    __syncthreads();
  }
  #pragma unroll
  for (int mi = 0; mi < 4; ++mi)
    #pragma unroll
    for (int r = 0; r < 4; ++r) {
      size_t rowoff = (size_t)(b * S_ + qt * 128 + wr * 64 + mi * 16 + hi * 4 + r) * 2048 +
                      kt * 128 + wc * 64 + rl;
      #pragma unroll
      for (int ni = 0; ni < 4; ++ni)
        attn[rowoff + ni * 16] = acc[mi][ni][r];
    }
}

// ---------------- launcher ----------------
extern "C" void kernel_launch(void* const* d_in, const int* in_sizes, int n_in,
                              void* d_out, int out_size, void* d_ws, size_t ws_size,
                              hipStream_t stream) {
  const float* query     = (const float*)d_in[0];
  const float* ln1_g     = (const float*)d_in[1];
  const float* ln1_b     = (const float*)d_in[2];
  const float* in_proj_w = (const float*)d_in[3];
  const float* in_proj_b = (const float*)d_in[4];
  const float* out_w     = (const float*)d_in[5];
  const float* out_b     = (const float*)d_in[6];
  const float* ln2_g     = (const float*)d_in[7];
  const float* ln2_b     = (const float*)d_in[8];
  const float* w1        = (const float*)d_in[9];
  const float* b1        = (const float*)d_in[10];
  const float* w2        = (const float*)d_in[11];
  const float* b2        = (const float*)d_in[12];

  u16* ws = (u16*)d_ws;
  u16* wq_bf = ws;                       // [1536,512]
  u16* wo_bf = wq_bf + 1536 * 512;       // [512,512]
  u16* w1_bf = wo_bf + 512 * 512;        // [2048,512]
  u16* w2_bf = w1_bf + 2048 * 512;       // [512,2048]
  u16* xq_bf = w2_bf + 512 * 2048;       // [8192,512]
  u16* qkv_bf = xq_bf + 8192 * 512;      // [8192,1536] (V section unused)
  u16* ctx_bf = qkv_bf + 8192 * 1536;    // [8192,512]
  u16* h_bf   = ctx_bf + 8192 * 512;     // [8192,512]
  u16* mh_bf  = h_bf + 8192 * 512;       // [8192,2048]
  float* rinv = (float*)(mh_bf + 8192 * 2048);  // [B*H*S]
  u16* vT = mh_bf;                       // [4,8,64,2048] alias (mh dead until MLP1)

  float* xout = (float*)d_out;                    // [8192,512]
  float* attn = xout + (size_t)8192 * 512;        // [4,2048,2048]

  // 1. weights -> bf16 (single fused launch)
  cvt4_k<<<3072, 256, 0, stream>>>(in_proj_w, wq_bf, out_w, wo_bf, w1, w1_bf, w2, w2_bf);

  // 2. LN1
  ln_k<<<2048, 256, 0, stream>>>(query, ln1_g, ln1_b, xq_bf);

  // 3. QKV projection (Q pre-scaled by log2e/8; V transposed to vT)
  gemm_nt<3><<<dim3(12, 64), 256, 0, stream>>>(xq_bf, wq_bf, in_proj_b, nullptr, qkv_bf, vT, 8192, 1536, 512);

  // 4. fused flash ctx (8-wave blocks; writes ctx + rinv)
  attn_fctx4_k<<<dim3(8, 8, 4), 512, 0, stream>>>(qkv_bf, vT, rinv, ctx_bf);

  // 5. head-mean probs -> attn_weight output (GEMM-shaped)
  attn_mean8_k<<<dim3(16, 16, 4), 256, 0, stream>>>(qkv_bf, rinv, attn);

  // 6. out-proj + residual(query) -> x (f32, d_out)
  gemm_nt<1><<<dim3(4, 64), 256, 0, stream>>>(ctx_bf, wo_bf, out_b, query, xout, nullptr, 8192, 512, 512);

  // 7. LN2 on x
  ln_k<<<2048, 256, 0, stream>>>(xout, ln2_g, ln2_b, h_bf);

  // 8. MLP up + GELU
  gemm_nt<2><<<dim3(16, 64), 256, 0, stream>>>(h_bf, w1_bf, b1, nullptr, mh_bf, nullptr, 8192, 2048, 512);

  // 9. MLP down + residual(x) -> final x (in-place on d_out x region)
  gemm_nt<1><<<dim3(4, 64), 256, 0, stream>>>(mh_bf, w2_bf, b2, xout, xout, nullptr, 8192, 512, 2048);
}